// Round 5
// baseline (482.173 us; speedup 1.0000x reference)
//
#include <hip/hip_runtime.h>

static constexpr int NN = 100000;   // nodes
static constexpr int NE = 1600000;  // edges
static constexpr int C  = 128;      // feature dim
static constexpr int OC = 10;       // output classes
static constexpr int NG = 512;      // graphs

// Bucketed CSR build parameters
static constexpr int BSH  = 9;                         // 512 nodes per bucket
static constexpr int BNW  = 1 << BSH;                  // 512
static constexpr int BK   = (NN + BNW - 1) / BNW;      // 196 buckets
static constexpr int BCAP = 12288;                     // slab capacity (avg ~8163)
static constexpr int EPB  = 8192;                      // edges per binA block
static constexpr int ABLK = (NE + EPB - 1) / EPB;      // 196
static constexpr int NSL  = 8;                         // src slices (src>>14 -> 0..6)

typedef unsigned short u16;
typedef __attribute__((ext_vector_type(8))) short short8;   // 8 bf16 = 16B
typedef __attribute__((ext_vector_type(8))) short bf16x8;   // MFMA A/B frag
typedef __attribute__((ext_vector_type(4))) float f32x4;    // MFMA C/D frag

__device__ __forceinline__ float bf2f(u16 u) {
    union { float f; unsigned int u32; } v; v.u32 = ((unsigned int)u) << 16; return v.f;
}
__device__ __forceinline__ u16 f2bf(float f) {
    union { float f; unsigned int u; } v; v.f = f;
    unsigned int u = v.u;
    unsigned int r = u + 0x7FFF + ((u >> 16) & 1);   // RNE
    return (u16)(r >> 16);
}

// ---------------------------------------------------------------------------
// Phase A: bin edges into BK buckets by dst>>BSH (L2-local slab writes).
// ---------------------------------------------------------------------------
__global__ __launch_bounds__(256) void k_binA(const int* __restrict__ src,
                                              const int* __restrict__ dst,
                                              int* __restrict__ gcnt,
                                              int* __restrict__ buck) {
    __shared__ int cnt[BK];
    __shared__ int curs[BK];
    int tid = threadIdx.x;
    for (int i = tid; i < BK; i += 256) cnt[i] = 0;
    __syncthreads();
    int e0 = blockIdx.x * EPB;
    for (int i = tid; i < EPB; i += 256) {
        int e = e0 + i;
        if (e < NE) atomicAdd(&cnt[dst[e] >> BSH], 1);
    }
    __syncthreads();
    for (int i = tid; i < BK; i += 256) {
        int c = cnt[i];
        int gb = (c > 0) ? atomicAdd(&gcnt[i], c) : 0;
        curs[i] = i * BCAP + gb;
    }
    __syncthreads();
    for (int i = tid; i < EPB; i += 256) {
        int e = e0 + i;
        if (e < NE) {
            int d = dst[e];
            int b = d >> BSH;
            int p = atomicAdd(&curs[b], 1);
            if (p < (b + 1) * BCAP)
                buck[p] = (src[e] << BSH) | (d & (BNW - 1));
        }
    }
}

// ---------------------------------------------------------------------------
// Exclusive scan of bucket counts -> per-bucket CSR base.  Also rp[NN]=NE.
// ---------------------------------------------------------------------------
__global__ void k_binscan(const int* __restrict__ gcnt, int* __restrict__ csrbase,
                          int* __restrict__ rp) {
    __shared__ int buf[256];
    int tid = threadIdx.x;
    int v = (tid < BK) ? gcnt[tid] : 0;
    buf[tid] = v;
    __syncthreads();
    for (int off = 1; off < 256; off <<= 1) {
        int t = (tid >= off) ? buf[tid - off] : 0;
        __syncthreads();
        buf[tid] += t;
        __syncthreads();
    }
    if (tid < BK) csrbase[tid] = buf[tid] - v;
    if (tid == 0) rp[NN] = NE;
}

// ---------------------------------------------------------------------------
// Phase B: one block per bucket.  Counting-sort the bucket's edges by
// (dst_local, src>>14): per-node lists end up src-region-ordered so that all
// concurrently-running gather blocks sweep the feature buffer together
// (moving-window L2 locality).  Also emits the rp slice.
// ---------------------------------------------------------------------------
__global__ __launch_bounds__(BNW) void k_binB(const int* __restrict__ gcnt,
                                              const int* __restrict__ csrbase,
                                              const int* __restrict__ buck,
                                              int* __restrict__ rp,
                                              int* __restrict__ csr) {
    int b = blockIdx.x;
    int tid = threadIdx.x;
    __shared__ int hist[BNW * NSL];   // (node,slice) histogram, then cursors
    __shared__ int part[BNW];         // per-node totals for block scan
    int n = gcnt[b];
    if (n > BCAP) n = BCAP;
    int base = csrbase[b];
    const int* bb = buck + (size_t)b * BCAP;

    for (int i = tid; i < BNW * NSL; i += BNW) hist[i] = 0;
    __syncthreads();
    for (int i = tid; i < n; i += BNW) {
        int en = bb[i];
        atomicAdd(&hist[((en & (BNW - 1)) << 3) | ((en >> BSH) >> 14)], 1);
    }
    __syncthreads();

    // per-node total
    int c0 = tid * NSL;
    int sum = 0;
#pragma unroll
    for (int q = 0; q < NSL; ++q) sum += hist[c0 + q];
    part[tid] = sum;
    __syncthreads();
    for (int off = 1; off < BNW; off <<= 1) {
        int t = (tid >= off) ? part[tid - off] : 0;
        __syncthreads();
        part[tid] += t;
        __syncthreads();
    }
    int excl = part[tid] - sum;               // exclusive node prefix
    int node = (b << BSH) + tid;
    if (node < NN) rp[node] = base + excl;

    // turn hist chunk into absolute cursors (node-major, slice-minor)
    int run = base + excl;
#pragma unroll
    for (int q = 0; q < NSL; ++q) { int h = hist[c0 + q]; hist[c0 + q] = run; run += h; }
    __syncthreads();

    for (int i = tid; i < n; i += BNW) {
        int en = bb[i];
        int s = en >> BSH;
        int p = atomicAdd(&hist[((en & (BNW - 1)) << 3) | (s >> 14)], 1);
        csr[p] = s;
    }
}

// ---------------------------------------------------------------------------
// f32 -> bf16 conversion (8 elems/thread)
// ---------------------------------------------------------------------------
__global__ void k_cvt_bf16(const float* __restrict__ in, u16* __restrict__ out) {
    int i = blockIdx.x * blockDim.x + threadIdx.x;
    size_t base = (size_t)i * 8;
    if (base >= (size_t)NN * C) return;
    float4 a = *reinterpret_cast<const float4*>(in + base);
    float4 b = *reinterpret_cast<const float4*>(in + base + 4);
    u16 o[8] = { f2bf(a.x), f2bf(a.y), f2bf(a.z), f2bf(a.w),
                 f2bf(b.x), f2bf(b.y), f2bf(b.z), f2bf(b.w) };
    *reinterpret_cast<short8*>(out + base) = *reinterpret_cast<const short8*>(o);
}

// ---------------------------------------------------------------------------
// Pack [W_rel; W_root] (256x128 f32) into per-lane MFMA B-fragment order, bf16.
// ---------------------------------------------------------------------------
__global__ void k_pack_w(const float* __restrict__ W_rel,
                         const float* __restrict__ W_root,
                         u16* __restrict__ Bp) {
    int t = blockIdx.x * blockDim.x + threadIdx.x;   // 0..4095
    if (t >= 4096) return;
    int lane = t & 63;
    int nfrag = (t >> 6) & 7;
    int kk = t >> 9;
    int col = nfrag * 16 + (lane & 15);
    int k0 = kk * 32 + (lane >> 4) * 8;
    u16 vals[8];
#pragma unroll
    for (int j = 0; j < 8; ++j) {
        int k = k0 + j;
        float w = (k < C) ? W_rel[k * C + col] : W_root[(k - C) * C + col];
        vals[j] = f2bf(w);
    }
    *reinterpret_cast<short8*>(Bp + (size_t)t * 8) = *reinterpret_cast<const short8*>(vals);
}

// ---------------------------------------------------------------------------
// Fused layer: per wave, 16 rows.  Gather accumulates the MFMA A-fragment
// slices directly in registers (lane l: row=l&15, k-cols koff+kk*32, koff=
// (l>>4)*8), then 64 MFMAs with packed weights, bias[+relu] epilogue.
// Reads hin (other rows too) -> must write a DIFFERENT buffer (ping-pong).
// ---------------------------------------------------------------------------
template <bool RELU>
__global__ __launch_bounds__(256) void k_layer(
    const u16* __restrict__ hin, const int* __restrict__ rp,
    const int* __restrict__ csr, const u16* __restrict__ Bp,
    const float* __restrict__ bias, u16* __restrict__ hout) {
    int lane = threadIdx.x & 63;
    int wave = threadIdx.x >> 6;
    int row0 = blockIdx.x * 64 + wave * 16;
    int row = row0 + (lane & 15);
    bool valid = row < NN;
    int rowc = valid ? row : NN - 1;
    int koff = (lane >> 4) * 8;

    int beg = 0, end = 0;
    if (valid) { beg = rp[row]; end = rp[row + 1]; }

    // ---- gather phase: agg slice in registers ----
    float ag[4][8];
#pragma unroll
    for (int kk = 0; kk < 4; ++kk)
#pragma unroll
        for (int q = 0; q < 8; ++q) ag[kk][q] = 0.0f;

    for (int j = beg; j < end; ++j) {
        int s = csr[j];
        const u16* rowp = hin + (size_t)s * C + koff;
#pragma unroll
        for (int kk = 0; kk < 4; ++kk) {
            short8 v = *reinterpret_cast<const short8*>(rowp + kk * 32);
#pragma unroll
            for (int q = 0; q < 8; ++q) ag[kk][q] += bf2f((u16)v[q]);
        }
    }

    // ---- MFMA phase ----
    f32x4 acc[8] = {};
#pragma unroll
    for (int kk = 0; kk < 8; ++kk) {
        bf16x8 a;
        if (kk < 4) {
            u16 tmp[8];
#pragma unroll
            for (int q = 0; q < 8; ++q) tmp[q] = f2bf(ag[kk][q]);
            a = *reinterpret_cast<const bf16x8*>(tmp);
        } else {
            a = *reinterpret_cast<const bf16x8*>(hin + (size_t)rowc * C + (kk - 4) * 32 + koff);
        }
        const u16* bp = Bp + ((size_t)kk * 8 * 64 + lane) * 8;
#pragma unroll
        for (int n = 0; n < 8; ++n) {
            bf16x8 bfr = *reinterpret_cast<const bf16x8*>(bp + (size_t)n * 64 * 8);
            acc[n] = __builtin_amdgcn_mfma_f32_16x16x32_bf16(a, bfr, acc[n], 0, 0, 0);
        }
    }

    // ---- epilogue: D layout col=lane&15, row=row0+(lane>>4)*4+r ----
    int colbase = lane & 15;
    int rowe = row0 + (lane >> 4) * 4;
#pragma unroll
    for (int n = 0; n < 8; ++n) {
        int col = n * 16 + colbase;
        float bb = bias[col];
#pragma unroll
        for (int r = 0; r < 4; ++r) {
            int ro = rowe + r;
            if (ro < NN) {
                float v = acc[n][r] + bb;
                if (RELU) v = fmaxf(v, 0.0f);
                hout[(size_t)ro * C + col] = f2bf(v);
            }
        }
    }
}

// ---------------------------------------------------------------------------
// Graph boundaries via binary search (batch is sorted), then fused pool+linear.
// ---------------------------------------------------------------------------
__global__ void k_gbounds(const int* __restrict__ batch, int* __restrict__ gstart) {
    int g = blockIdx.x * blockDim.x + threadIdx.x;
    if (g > NG) return;
    int lo = 0, hi = NN;
    while (lo < hi) { int mid = (lo + hi) >> 1; if (batch[mid] < g) lo = mid + 1; else hi = mid; }
    gstart[g] = lo;
}

__global__ void k_pool_final(const u16* __restrict__ h, const int* __restrict__ gstart,
                             const float* __restrict__ W_lin, const float* __restrict__ b_lin,
                             float* __restrict__ out) {
    int g = blockIdx.x;
    int c = threadIdx.x;  // 128 threads
    int s = gstart[g], e = gstart[g + 1];
    float acc = 0.0f;
    for (int i = s; i < e; ++i) acc += bf2f(h[(size_t)i * C + c]);
    __shared__ float sp[C];
    float cnt = (float)max(e - s, 1);
    sp[c] = acc / cnt;
    __syncthreads();
    if (c < OC) {
        float o = b_lin[c];
#pragma unroll 8
        for (int k = 0; k < C; ++k) o += sp[k] * W_lin[k * OC + c];
        out[g * OC + c] = o;
    }
}

extern "C" void kernel_launch(void* const* d_in, const int* in_sizes, int n_in,
                              void* d_out, int out_size, void* d_ws, size_t ws_size,
                              hipStream_t stream) {
    const float* x       = (const float*)d_in[0];
    const int*   eidx    = (const int*)d_in[1];
    const int*   batch   = (const int*)d_in[2];
    const float* W1_rel  = (const float*)d_in[3];
    const float* b1      = (const float*)d_in[4];
    const float* W1_root = (const float*)d_in[5];
    const float* W2_rel  = (const float*)d_in[6];
    const float* b2      = (const float*)d_in[7];
    const float* W2_root = (const float*)d_in[8];
    const float* W3_rel  = (const float*)d_in[9];
    const float* b3      = (const float*)d_in[10];
    const float* W3_root = (const float*)d_in[11];
    const float* W_lin   = (const float*)d_in[12];
    const float* b_lin   = (const float*)d_in[13];
    float* out = (float*)d_out;

    const int* src = eidx;
    const int* dst = eidx + NE;

    // Workspace layout
    u16* xb   = (u16*)d_ws;                       // NN*C bf16
    u16* h1   = xb + (size_t)NN * C;              // NN*C bf16
    u16* h2   = h1 + (size_t)NN * C;              // NN*C bf16
    u16* Bp   = h2 + (size_t)NN * C;              // 3 * 32768 bf16
    int* rp      = (int*)(Bp + 3 * 32768);        // NN+1
    int* csr     = rp + NN + 1;                   // NE
    int* buck    = csr + NE;                      // BK*BCAP
    int* gcnt    = buck + (size_t)BK * BCAP;      // BK
    int* csrbase = gcnt + BK;                     // BK
    int* gstart  = csrbase + BK;                  // NG+1

    const int tb = (NN + 63) / 64;                // fused layer blocks
    const int cvtb = ((NN * C / 8) + 255) / 256;

    // ---- Bucketed CSR build (shared by all 3 layers) ----
    hipMemsetAsync(gcnt, 0, BK * sizeof(int), stream);
    k_binA<<<ABLK, 256, 0, stream>>>(src, dst, gcnt, buck);
    k_binscan<<<1, 256, 0, stream>>>(gcnt, csrbase, rp);
    k_binB<<<BK, BNW, 0, stream>>>(gcnt, csrbase, buck, rp, csr);

    // ---- Precompute: x->bf16, packed weights, graph bounds ----
    k_cvt_bf16<<<cvtb, 256, 0, stream>>>(x, xb);
    k_pack_w<<<16, 256, 0, stream>>>(W1_rel, W1_root, Bp);
    k_pack_w<<<16, 256, 0, stream>>>(W2_rel, W2_root, Bp + 32768);
    k_pack_w<<<16, 256, 0, stream>>>(W3_rel, W3_root, Bp + 2 * 32768);
    k_gbounds<<<3, 256, 0, stream>>>(batch, gstart);

    // ---- Fused layers (ping-pong) ----
    k_layer<true><<<tb, 256, 0, stream>>>(xb, rp, csr, Bp, b1, h1);
    k_layer<true><<<tb, 256, 0, stream>>>(h1, rp, csr, Bp + 32768, b2, h2);
    k_layer<false><<<tb, 256, 0, stream>>>(h2, rp, csr, Bp + 2 * 32768, b3, h1);

    // ---- Fused pool + final linear ----
    k_pool_final<<<NG, C, 0, stream>>>(h1, gstart, W_lin, b_lin, out);
}